// Round 2
// baseline (96674.677 us; speedup 1.0000x reference)
//
#include <hip/hip_runtime.h>
#include <math.h>

#define NN 1024
#define PP 20

// ---------- cost: replicate reference fp32 op order exactly ----------
__device__ __forceinline__ float cost_ij(const float* __restrict__ a,
                                         const float* __restrict__ b) {
#pragma clang fp contract(off)
  float s = 0.0f;
#pragma unroll
  for (int p = 0; p < PP; ++p) {
    float dx = a[2 * p]     - b[2 * p];
    float dy = a[2 * p + 1] - b[2 * p + 1];
    s += sqrtf(dx * dx + dy * dy);
  }
  return s / 20.0f;
}

__global__ void cost_kernel(const float* __restrict__ pred,
                            const float* __restrict__ gt,
                            float* __restrict__ cost) {
  int id = blockIdx.x * blockDim.x + threadIdx.x;  // 0 .. NN*NN-1
  int i = id >> 10;
  int j = id & (NN - 1);
  cost[id] = cost_ij(pred + i * 40, gt + j * 40);
}

// ---------- LAP: single-wave Jonker-Volgenant (barrier-free) ----------
// 64 lanes, 16 columns per lane (col = 64*q + lane, coalesced).
// v, shortest, SC live in registers; u, path, col4row, row4col in LDS.
// Bit-exact vs the numpy reference: fp64 arithmetic in identical op order,
// exact min reduction, first-index tie-break via lexicographic (key,col).
__global__ __launch_bounds__(64) void lap_wave_kernel(
    const float* __restrict__ gt, const float* __restrict__ cost,
    float* __restrict__ out) {
  const int lane = threadIdx.x;
  const double INF = __builtin_inf();

  __shared__ double u_s[NN];
  __shared__ int path_s[NN];
  __shared__ int col4row_s[NN];
  __shared__ int row4col_s[NN];

  double v_r[16];
  double sh_r[16];
  unsigned sc_mask;

#pragma unroll
  for (int q = 0; q < 16; ++q) {
    v_r[q] = 0.0;
    u_s[q * 64 + lane] = 0.0;
    col4row_s[q * 64 + lane] = -1;
    row4col_s[q * 64 + lane] = -1;
  }

  for (int r = 0; r < NN; ++r) {
#pragma unroll
    for (int q = 0; q < 16; ++q) sh_r[q] = INF;
    sc_mask = 0u;

    int i = r;
    double mv = 0.0;
    int sink = -1;

    while (true) {
      const double u_i = u_s[i];
      const float* crow = cost + (size_t)i * NN;

      // issue all 16 coalesced loads unconditionally (compiler clusters them)
      float c[16];
#pragma unroll
      for (int q = 0; q < 16; ++q) c[q] = crow[q * 64 + lane];

      // relax + in-lane candidate (ascending q => ascending col; strict <
      // keeps the first index among ties)
      double bk = INF;
      int bc = 0x7fffffff;
#pragma unroll
      for (int q = 0; q < 16; ++q) {
        if (!((sc_mask >> q) & 1u)) {
          // exact numpy order: ((mv + c) - u[i]) - v[j]
          double d = (mv + (double)c[q]) - u_i - v_r[q];
          if (d < sh_r[q]) {
            sh_r[q] = d;
            path_s[q * 64 + lane] = i;
          }
          if (sh_r[q] < bk) {
            bk = sh_r[q];
            bc = q * 64 + lane;
          }
        }
      }

      // 6-level butterfly: lexicographic (key, col) min across 64 lanes
#pragma unroll
      for (int m = 1; m < 64; m <<= 1) {
        double k2 = __shfl_xor(bk, m);
        int c2 = __shfl_xor(bc, m);
        if (k2 < bk || (k2 == bk && c2 < bc)) {
          bk = k2;
          bc = c2;
        }
      }

      mv = bk;  // == shortest[kcol], bit-identical (exact min)
      const int kcol = bc;
      if ((kcol & 63) == lane) sc_mask |= 1u << (kcol >> 6);

      const int rc = row4col_s[kcol];  // uniform address -> broadcast
      if (rc < 0) {
        sink = kcol;
        break;
      }
      i = rc;
    }

    // ---- dual update (exact numpy op order) ----
    if (lane == 0) u_s[r] += mv;
#pragma unroll
    for (int q = 0; q < 16; ++q) {
      if ((sc_mask >> q) & 1u) {
        const int k = q * 64 + lane;
        const double delta = mv - sh_r[q];
        const int i2 = row4col_s[k];
        if (i2 >= 0) u_s[i2] += delta;  // distinct i2 per k (injective)
        v_r[q] = v_r[q] - delta;
      }
    }

    // ---- augment walk (serial, lane 0) ----
    if (lane == 0) {
      int j = sink;
      while (true) {
        const int i2 = path_s[j];
        row4col_s[j] = i2;
        const int jn = col4row_s[i2];
        col4row_s[i2] = j;
        j = jn;
        if (i2 == r) break;
      }
    }
  }

  // ---------- outputs: 16 rows per lane ----------
#pragma unroll
  for (int q = 0; q < 16; ++q) {
    const int row = q * 64 + lane;
    const int col = col4row_s[row];
    const float4* g4 = reinterpret_cast<const float4*>(gt + (size_t)col * 40);
    float4* o4 = reinterpret_cast<float4*>(out + (size_t)row * 40);
#pragma unroll
    for (int w = 0; w < 10; ++w) o4[w] = g4[w];
    const float cc = cost[(size_t)row * NN + col];
    out[NN * 40 + row] = expf(-cc);
  }
}

extern "C" void kernel_launch(void* const* d_in, const int* in_sizes, int n_in,
                              void* d_out, int out_size, void* d_ws,
                              size_t ws_size, hipStream_t stream) {
  const float* pred = (const float*)d_in[0];
  const float* gt = (const float*)d_in[1];
  float* out = (float*)d_out;
  float* cost = (float*)d_ws;

  cost_kernel<<<NN * NN / 256, 256, 0, stream>>>(pred, gt, cost);
  lap_wave_kernel<<<1, 64, 0, stream>>>(gt, cost, out);
}

// Round 3
// 29269.702 us; speedup vs baseline: 3.3029x; 3.3029x over previous
//
#include <hip/hip_runtime.h>
#include <math.h>

#define NN 1024
#define PP 20
#define LPC 16  // columns per lane (64 lanes x 16 = 1024)

// ---------- cost: same fp32 op order as reference ----------
__device__ __forceinline__ float cost_ij(const float* __restrict__ a,
                                         const float* __restrict__ b) {
#pragma clang fp contract(off)
  float s = 0.0f;
#pragma unroll
  for (int p = 0; p < PP; ++p) {
    float dx = a[2 * p]     - b[2 * p];
    float dy = a[2 * p + 1] - b[2 * p + 1];
    s += sqrtf(dx * dx + dy * dy);
  }
  return s / 20.0f;
}

__global__ void cost_kernel(const float* __restrict__ pred,
                            const float* __restrict__ gt,
                            float* __restrict__ cost) {
  int id = blockIdx.x * blockDim.x + threadIdx.x;  // 0 .. NN*NN-1
  int i = id >> 10;
  int j = id & (NN - 1);
  cost[id] = cost_ij(pred + i * 40, gt + j * 40);
}

// ---------- column minima: v0[j] = min_i cost[i][j], first argmin ----------
__global__ void colmin_kernel(const float* __restrict__ cost,
                              float* __restrict__ colv,
                              int* __restrict__ colr) {
  int j = blockIdx.x * blockDim.x + threadIdx.x;  // 1024 threads total
  float mv = cost[j];
  int mi = 0;
#pragma unroll 8
  for (int i = 1; i < NN; ++i) {
    float c = cost[i * NN + j];
    if (c < mv) { mv = c; mi = i; }
  }
  colv[j] = mv;
  colr[j] = mi;
}

// ---------- warm-started Jonker-Volgenant, single wave ----------
// Phase 1: column-reduction greedy assignment (feasible duals u=0, v=colmin).
// Phase 2: JV87 augmenting row reduction, 4 bounded passes.
// Phase 3: shortest-augmenting-path (Dijkstra) for remaining free rows.
// Feasible duals + complementary slackness throughout => final matching is
// the optimal assignment (== reference output given a unique optimum).
__global__ __launch_bounds__(64) void lap_warm_kernel(
    const float* __restrict__ gt, const float* __restrict__ cost,
    const float* __restrict__ colv, const int* __restrict__ colr,
    float* __restrict__ out) {
  const int lane = threadIdx.x;
  const double INF = __builtin_inf();

  __shared__ double u_s[NN];
  __shared__ int row4col_s[NN];
  __shared__ int col4row_s[NN];
  __shared__ int path_s[NN];

  double v_r[LPC];   // v duals for owned cols [lane*16, lane*16+16)
  double sh_r[LPC];  // Dijkstra shortest
  int pa_r[LPC];     // predecessor row per owned col
  int rc_r[LPC];     // register mirror of row4col for owned cols
  unsigned sc;       // SC bitmask for owned cols

#pragma unroll
  for (int q = 0; q < LPC; ++q) {
    const int j = lane * LPC + q;
    v_r[q] = (double)colv[j];
    u_s[j] = 0.0;
    row4col_s[j] = -1;
    col4row_s[j] = -1;
  }
  __syncthreads();

  // ---- phase 1: greedy claim (serial, deterministic) ----
  if (lane == 0) {
    for (int j = 0; j < NN; ++j) {
      const int i = colr[j];
      if (col4row_s[i] < 0) { col4row_s[i] = j; row4col_s[j] = i; }
    }
  }
  __syncthreads();

  // ---- phase 2: augmenting row reduction (JV87), bounded passes ----
  for (int pass = 0; pass < 4; ++pass) {
    for (int i = 0; i < NN; ++i) {
      if (col4row_s[i] >= 0) continue;  // uniform branch (same LDS word)
      const float* crow = cost + (size_t)i * NN + lane * LPC;
      float c[LPC];
#pragma unroll
      for (int x = 0; x < 4; ++x) {
        float4 f = ((const float4*)crow)[x];
        c[4 * x + 0] = f.x; c[4 * x + 1] = f.y;
        c[4 * x + 2] = f.z; c[4 * x + 3] = f.w;
      }
      // two smallest reduced costs of row i (+ first-argmin col of min1)
      double m1 = INF, m2 = INF;
      int c1 = 0x7fffffff;
#pragma unroll
      for (int q = 0; q < LPC; ++q) {
        const double d = (double)c[q] - v_r[q];
        if (d < m1) { m2 = m1; m1 = d; c1 = lane * LPC + q; }
        else if (d < m2) m2 = d;
      }
#pragma unroll
      for (int m = 1; m < 64; m <<= 1) {
        const double pm1 = __shfl_xor(m1, m);
        const double pm2 = __shfl_xor(m2, m);
        const int pc1 = __shfl_xor(c1, m);
        const double nm2 = fmin(fmax(m1, pm1), fmin(m2, pm2));
        if (pm1 < m1 || (pm1 == m1 && pc1 < c1)) { m1 = pm1; c1 = pc1; }
        m2 = nm2;
      }
      const int j1 = c1;          // uniform after butterfly
      const double delta = m2 - m1;
      if (lane == 0) u_s[i] = m2;
      if (m1 < m2) {
#pragma unroll
        for (int q = 0; q < LPC; ++q)
          if (lane * LPC + q == j1) v_r[q] -= delta;  // v[j1] = c[i,j1]-u2
      }
      const int k = row4col_s[j1];  // uniform read, pre-write value
      __syncthreads();
      if (lane == 0) {
        row4col_s[j1] = i;
        col4row_s[i] = j1;
        if (k >= 0) col4row_s[k] = -1;  // displaced row re-enters later
      }
      __syncthreads();
    }
  }

#pragma unroll
  for (int q = 0; q < LPC; ++q) rc_r[q] = row4col_s[lane * LPC + q];
  __syncthreads();

  // ---- phase 3: Dijkstra augmentation for remaining free rows ----
  for (int r = 0; r < NN; ++r) {
    if (col4row_s[r] >= 0) continue;
#pragma unroll
    for (int q = 0; q < LPC; ++q) sh_r[q] = INF;
    sc = 0u;
    int i = r;
    double mv = 0.0;
    double u_i = u_s[r];
    int sink;
    while (true) {
      const float* crow = cost + (size_t)i * NN + lane * LPC;
      float c[LPC];
#pragma unroll
      for (int x = 0; x < 4; ++x) {
        float4 f = ((const float4*)crow)[x];
        c[4 * x + 0] = f.x; c[4 * x + 1] = f.y;
        c[4 * x + 2] = f.z; c[4 * x + 3] = f.w;
      }
      const double a = mv - u_i;
#pragma unroll
      for (int q = 0; q < LPC; ++q) {
        if (!((sc >> q) & 1u)) {
          const double d = (a + (double)c[q]) - v_r[q];
          if (d < sh_r[q]) { sh_r[q] = d; pa_r[q] = i; }
        }
      }
      // in-lane 4-level tree over masked keys, carrying (key, e, rc)
      double kq[LPC];
#pragma unroll
      for (int q = 0; q < LPC; ++q)
        kq[q] = ((sc >> q) & 1u) ? INF : sh_r[q];
      double t1k[8]; int t1e[8], t1r[8];
#pragma unroll
      for (int q = 0; q < 8; ++q) {
        const bool b = kq[2 * q + 1] < kq[2 * q];
        t1k[q] = b ? kq[2 * q + 1] : kq[2 * q];
        t1e[q] = b ? 2 * q + 1 : 2 * q;
        t1r[q] = b ? rc_r[2 * q + 1] : rc_r[2 * q];
      }
      double t2k[4]; int t2e[4], t2r[4];
#pragma unroll
      for (int q = 0; q < 4; ++q) {
        const bool b = t1k[2 * q + 1] < t1k[2 * q];
        t2k[q] = b ? t1k[2 * q + 1] : t1k[2 * q];
        t2e[q] = b ? t1e[2 * q + 1] : t1e[2 * q];
        t2r[q] = b ? t1r[2 * q + 1] : t1r[2 * q];
      }
      double t3k[2]; int t3e[2], t3r[2];
#pragma unroll
      for (int q = 0; q < 2; ++q) {
        const bool b = t2k[2 * q + 1] < t2k[2 * q];
        t3k[q] = b ? t2k[2 * q + 1] : t2k[2 * q];
        t3e[q] = b ? t2e[2 * q + 1] : t2e[2 * q];
        t3r[q] = b ? t2r[2 * q + 1] : t2r[2 * q];
      }
      const bool b0 = t3k[1] < t3k[0];
      double bk = b0 ? t3k[1] : t3k[0];
      int be = b0 ? t3e[1] : t3e[0];
      int brc = b0 ? t3r[1] : t3r[0];
      int bcol = lane * LPC + be;
      // cross-lane butterfly carrying (key, col, rc); ties -> lowest col
#pragma unroll
      for (int m = 1; m < 64; m <<= 1) {
        const double k2 = __shfl_xor(bk, m);
        const int c2 = __shfl_xor(bcol, m);
        const int r2 = __shfl_xor(brc, m);
        if (k2 < bk || (k2 == bk && c2 < bcol)) { bk = k2; bcol = c2; brc = r2; }
      }
      mv = bk;
      const int kcol = __builtin_amdgcn_readfirstlane(bcol);
      const int krc = __builtin_amdgcn_readfirstlane(brc);
      if (lane == (kcol >> 4)) sc |= 1u << (kcol & 15);
      if (krc < 0) { sink = kcol; break; }  // scalar branch
      i = krc;
      u_i = u_s[i];  // overlaps with next row's loads
    }
    // dual updates (pre-augmentation rc_r); path dump for the walk
#pragma unroll
    for (int q = 0; q < LPC; ++q) {
      if ((sc >> q) & 1u) {
        const double delta = mv - sh_r[q];
        const int i2 = rc_r[q];
        if (i2 >= 0) u_s[i2] += delta;  // distinct addresses (injective)
        v_r[q] -= delta;
      }
      path_s[lane * LPC + q] = pa_r[q];
    }
    if (lane == 0) u_s[r] += mv;
    __syncthreads();
    if (lane == 0) {
      int j = sink;
      while (true) {
        const int i2 = path_s[j];
        row4col_s[j] = i2;
        const int jn = col4row_s[i2];
        col4row_s[i2] = j;
        j = jn;
        if (i2 == r) break;
      }
    }
    __syncthreads();
#pragma unroll
    for (int q = 0; q < LPC; ++q) rc_r[q] = row4col_s[lane * LPC + q];
  }

  __syncthreads();
  // ---------- outputs ----------
#pragma unroll
  for (int q = 0; q < LPC; ++q) {
    const int row = lane * LPC + q;
    const int col = col4row_s[row];
    const float4* g4 = (const float4*)(gt + (size_t)col * 40);
    float4* o4 = (float4*)(out + (size_t)row * 40);
#pragma unroll
    for (int w = 0; w < 10; ++w) o4[w] = g4[w];
    out[NN * 40 + row] = expf(-cost[(size_t)row * NN + col]);
  }
}

extern "C" void kernel_launch(void* const* d_in, const int* in_sizes, int n_in,
                              void* d_out, int out_size, void* d_ws,
                              size_t ws_size, hipStream_t stream) {
  const float* pred = (const float*)d_in[0];
  const float* gt = (const float*)d_in[1];
  float* out = (float*)d_out;
  float* cost = (float*)d_ws;  // 4 MB (proven available in R1)

  // colmin scratch lives in d_out (first 2048 floats); consumed in the
  // lap kernel prologue, overwritten by the real outputs at its end.
  float* colv = out;
  int* colr = (int*)(out + NN);

  cost_kernel<<<NN * NN / 256, 256, 0, stream>>>(pred, gt, cost);
  colmin_kernel<<<NN / 256, 256, 0, stream>>>(cost, colv, colr);
  lap_warm_kernel<<<1, 64, 0, stream>>>(gt, cost, colv, colr, out);
}

// Round 4
// 22915.976 us; speedup vs baseline: 4.2187x; 1.2773x over previous
//
#include <hip/hip_runtime.h>
#include <math.h>

#define NN 1024
#define PP 20
#define LPC 16                 // columns per lane (64 x 16 = 1024)
#define SCALE_D 33554432.0     // 2^25
#define INV_SCALE_F (1.0f / 33554432.0f)
#define IMAX 0x7fffffff

// ---------- cost: replicate reference fp32 op order exactly ----------
__device__ __forceinline__ float cost_ij(const float* __restrict__ a,
                                         const float* __restrict__ b) {
#pragma clang fp contract(off)
  float s = 0.0f;
#pragma unroll
  for (int p = 0; p < PP; ++p) {
    float dx = a[2 * p]     - b[2 * p];
    float dy = a[2 * p + 1] - b[2 * p + 1];
    s += sqrtf(dx * dx + dy * dy);
  }
  return s / 20.0f;
}

// Quantized cost: c * 2^25 is an exact integer for all entries in [2^-2, 2^3]
// (fp32 ulp <= 2^-25 there). Computed in double => exact product + exact cast.
__global__ void cost_kernel(const float* __restrict__ pred,
                            const float* __restrict__ gt,
                            int* __restrict__ ci) {
  int id = blockIdx.x * blockDim.x + threadIdx.x;  // 0 .. NN*NN-1
  int i = id >> 10;
  int j = id & (NN - 1);
  float c = cost_ij(pred + i * 40, gt + j * 40);
  ci[id] = (int)((double)c * SCALE_D);
}

// ---------- column minima: colv[j] = min_i ci[i][j], first argmin ----------
__global__ void colmin_kernel(const int* __restrict__ ci,
                              int* __restrict__ colv,
                              int* __restrict__ colr) {
  int j = blockIdx.x * blockDim.x + threadIdx.x;  // 1024 threads total
  int mv = ci[j];
  int mi = 0;
#pragma unroll 8
  for (int i = 1; i < NN; ++i) {
    int c = ci[i * NN + j];
    if (c < mv) { mv = c; mi = i; }
  }
  colv[j] = mv;
  colr[j] = mi;
}

// ---------- per-row top-2 reduced costs vs v0 (for reduction transfer) ----
__global__ __launch_bounds__(64) void rowmin_kernel(
    const int* __restrict__ ci, const int* __restrict__ colv,
    int* __restrict__ rm1, int* __restrict__ rm2, int* __restrict__ rj1) {
  const int row = blockIdx.x;
  const int lane = threadIdx.x;
  const int* cr = ci + (size_t)row * NN + lane * LPC;
  const int* vr = colv + lane * LPC;
  int4 ca = ((const int4*)cr)[0], cb = ((const int4*)cr)[1],
       cc = ((const int4*)cr)[2], cd = ((const int4*)cr)[3];
  int4 va = ((const int4*)vr)[0], vb = ((const int4*)vr)[1],
       vc = ((const int4*)vr)[2], vd = ((const int4*)vr)[3];
  int c[LPC] = {ca.x, ca.y, ca.z, ca.w, cb.x, cb.y, cb.z, cb.w,
                cc.x, cc.y, cc.z, cc.w, cd.x, cd.y, cd.z, cd.w};
  int v[LPC] = {va.x, va.y, va.z, va.w, vb.x, vb.y, vb.z, vb.w,
                vc.x, vc.y, vc.z, vc.w, vd.x, vd.y, vd.z, vd.w};
  int m1 = IMAX, m2 = IMAX, c1 = IMAX;
#pragma unroll
  for (int q = 0; q < LPC; ++q) {
    const int d = c[q] - v[q];
    if (d < m1) { m2 = m1; m1 = d; c1 = lane * LPC + q; }
    else if (d < m2) m2 = d;
  }
#pragma unroll
  for (int m = 1; m < 64; m <<= 1) {
    const int pm1 = __shfl_xor(m1, m);
    const int pm2 = __shfl_xor(m2, m);
    const int pc1 = __shfl_xor(c1, m);
    const int hi = (m1 > pm1) ? m1 : pm1;
    const int lo2 = (m2 < pm2) ? m2 : pm2;
    if (pm1 < m1 || (pm1 == m1 && pc1 < c1)) { m1 = pm1; c1 = pc1; }
    m2 = (hi < lo2) ? hi : lo2;
  }
  if (lane == 0) { rm1[row] = m1; rm2[row] = m2; rj1[row] = c1; }
}

// ---------- integer JV: greedy + RT + adaptive ARR + Dijkstra ----------
__global__ __launch_bounds__(64) void lap_kernel(
    const float* __restrict__ gt, const int* __restrict__ ci,
    const int* __restrict__ colv, const int* __restrict__ colr,
    const int* __restrict__ rm1, const int* __restrict__ rm2,
    const int* __restrict__ rj1, float* __restrict__ out) {
  const int lane = threadIdx.x;

  __shared__ int u_s[NN];
  __shared__ int row4col_s[NN];
  __shared__ int col4row_s[NN];
  __shared__ int path_s[NN];
  __shared__ int fla[NN];
  __shared__ int flb[NN];
  __shared__ int cnt_s;

  int v_r[LPC];   // v duals for owned cols [lane*16, lane*16+16)
  int sh_r[LPC];  // Dijkstra labels
  int pa_r[LPC];  // predecessor row per owned col
  int rc_r[LPC];  // register mirror of row4col for owned cols
  unsigned sc;    // settled bitmask for owned cols

#pragma unroll
  for (int q = 0; q < LPC; ++q) {
    const int j = lane * LPC + q;
    u_s[j] = 0;
    row4col_s[j] = -1;
    col4row_s[j] = -1;
  }
  __syncthreads();

  // ---- phase 1: greedy claim via column argmins (serial, deterministic) ----
  if (lane == 0) {
    for (int j = 0; j < NN; ++j) {
      const int i = colr[j];
      if (col4row_s[i] < 0) { col4row_s[i] = j; row4col_s[j] = i; }
    }
  }
  __syncthreads();

  // ---- reduction transfer (Jacobi-parallel, integer-exact feasible) ----
  // For assigned (i, j) with i == colr[j]: c[i][j] == colv[j], so
  // u[i] = mu_i = min_{j'!=j}(c[i][j'] - v0[j']), v[j] = colv[j] - mu_i
  // keeps all reduced costs >= 0 with the matched edge tight.
#pragma unroll
  for (int q = 0; q < LPC; ++q) {
    const int j = lane * LPC + q;
    const int i = row4col_s[j];
    int vv = colv[j];
    if (i >= 0) {
      const int mu = (rj1[i] == j) ? rm2[i] : rm1[i];
      u_s[i] = mu;  // injective (row4col is injective)
      vv -= mu;
    }
    v_r[q] = vv;
  }
  if (lane == 0) {
    int n = 0;
    for (int i = 0; i < NN; ++i)
      if (col4row_s[i] < 0) fla[n++] = i;
    cnt_s = n;
  }
  __syncthreads();

  // ---- phase 2: augmenting row reduction, free-list driven, adaptive ----
  int use_a = 1;
  int prev = NN + 1;
  for (int pass = 0; pass < 16; ++pass) {
    const int cnt = cnt_s;
    if (cnt == 0 || cnt >= prev) break;  // done or no strict progress
    prev = cnt;
    int n2 = 0;  // lane 0's next-list count
    for (int idx = 0; idx < cnt; ++idx) {
      const int i = use_a ? fla[idx] : flb[idx];
      const int* cr = ci + (size_t)i * NN + lane * LPC;
      int4 ca = ((const int4*)cr)[0], cb = ((const int4*)cr)[1],
           cc = ((const int4*)cr)[2], cd = ((const int4*)cr)[3];
      int c[LPC] = {ca.x, ca.y, ca.z, ca.w, cb.x, cb.y, cb.z, cb.w,
                    cc.x, cc.y, cc.z, cc.w, cd.x, cd.y, cd.z, cd.w};
      int m1 = IMAX, m2 = IMAX, c1 = IMAX;
#pragma unroll
      for (int q = 0; q < LPC; ++q) {
        const int d = c[q] - v_r[q];
        if (d < m1) { m2 = m1; m1 = d; c1 = lane * LPC + q; }
        else if (d < m2) m2 = d;
      }
#pragma unroll
      for (int m = 1; m < 64; m <<= 1) {
        const int pm1 = __shfl_xor(m1, m);
        const int pm2 = __shfl_xor(m2, m);
        const int pc1 = __shfl_xor(c1, m);
        const int hi = (m1 > pm1) ? m1 : pm1;
        const int lo2 = (m2 < pm2) ? m2 : pm2;
        if (pm1 < m1 || (pm1 == m1 && pc1 < c1)) { m1 = pm1; c1 = pc1; }
        m2 = (hi < lo2) ? hi : lo2;
      }
      const int j1 = c1;          // uniform after tie-broken butterfly
      const int delta = m2 - m1;  // >= 0
      if (lane == (j1 >> 4) && delta > 0) {
#pragma unroll
        for (int q = 0; q < LPC; ++q)
          if (q == (j1 & 15)) v_r[q] -= delta;  // v[j1] = c[i][j1] - m2
      }
      const int k = row4col_s[j1];  // uniform read, pre-write value
      __syncthreads();
      if (lane == 0) {
        u_s[i] = m2;
        row4col_s[j1] = i;
        col4row_s[i] = j1;
        if (k >= 0) {
          col4row_s[k] = -1;
          if (use_a) flb[n2] = k; else fla[n2] = k;
          ++n2;
        }
      }
      __syncthreads();
    }
    if (lane == 0) cnt_s = n2;
    use_a ^= 1;
    __syncthreads();
  }

#pragma unroll
  for (int q = 0; q < LPC; ++q) rc_r[q] = row4col_s[lane * LPC + q];
  __syncthreads();

  // ---- phase 3: integer Dijkstra augmentation for remaining free rows ----
  const int nfree = cnt_s;
  for (int fi = 0; fi < nfree; ++fi) {
    const int r = use_a ? fla[fi] : flb[fi];
#pragma unroll
    for (int q = 0; q < LPC; ++q) sh_r[q] = IMAX;
    sc = 0u;
    int i = r;
    int mv = 0;
    int u_i = u_s[r];
    int sink;
    while (true) {
      const int* cr = ci + (size_t)i * NN + lane * LPC;
      int4 ca = ((const int4*)cr)[0], cb = ((const int4*)cr)[1],
           cc = ((const int4*)cr)[2], cd = ((const int4*)cr)[3];
      int c[LPC] = {ca.x, ca.y, ca.z, ca.w, cb.x, cb.y, cb.z, cb.w,
                    cc.x, cc.y, cc.z, cc.w, cd.x, cd.y, cd.z, cd.w};
      const int A = mv - u_i;
#pragma unroll
      for (int q = 0; q < LPC; ++q) {
        if (!((sc >> q) & 1u)) {
          const int d = A + c[q] - v_r[q];
          if (d < sh_r[q]) { sh_r[q] = d; pa_r[q] = i; }
        }
      }
      // in-lane argmin (strict < keeps lowest q), carrying matched row
      int bs = IMAX, bc = IMAX, brc = -1;
#pragma unroll
      for (int q = 0; q < LPC; ++q) {
        const int key = ((sc >> q) & 1u) ? IMAX : sh_r[q];
        if (key < bs) { bs = key; bc = lane * LPC + q; brc = rc_r[q]; }
      }
      // cross-lane butterfly; tie-break lowest col => uniform result
#pragma unroll
      for (int m = 1; m < 64; m <<= 1) {
        const int ps = __shfl_xor(bs, m);
        const int pc = __shfl_xor(bc, m);
        const int pr = __shfl_xor(brc, m);
        if (ps < bs || (ps == bs && pc < bc)) { bs = ps; bc = pc; brc = pr; }
      }
      mv = bs;
      const int kcol = bc;
      if (lane == (kcol >> 4)) sc |= 1u << (kcol & 15);
      if (brc < 0) { sink = kcol; break; }
      i = brc;
      u_i = u_s[i];  // uniform LDS read, overlaps next row's loads
    }
    // dual updates (pre-augmentation rc_r) + path dump
#pragma unroll
    for (int q = 0; q < LPC; ++q) {
      if ((sc >> q) & 1u) {
        const int delta = mv - sh_r[q];
        const int i2 = rc_r[q];
        if (i2 >= 0) u_s[i2] += delta;  // injective addresses
        v_r[q] -= delta;
      }
      path_s[lane * LPC + q] = pa_r[q];
    }
    if (lane == 0) u_s[r] += mv;
    __syncthreads();
    if (lane == 0) {
      int j = sink;
      while (true) {
        const int i2 = path_s[j];
        row4col_s[j] = i2;
        const int jn = col4row_s[i2];
        col4row_s[i2] = j;
        j = jn;
        if (i2 == r) break;
      }
    }
    __syncthreads();
#pragma unroll
    for (int q = 0; q < LPC; ++q) rc_r[q] = row4col_s[lane * LPC + q];
  }
  __syncthreads();

  // ---------- outputs: 16 rows per lane ----------
#pragma unroll
  for (int q = 0; q < LPC; ++q) {
    const int row = lane * LPC + q;
    const int col = col4row_s[row];
    const float4* g4 = (const float4*)(gt + (size_t)col * 40);
    float4* o4 = (float4*)(out + (size_t)row * 40);
#pragma unroll
    for (int w = 0; w < 10; ++w) o4[w] = g4[w];
    // exact fp32 recovery: ci has <=24 significant bits, scale is pow2
    const float cf = (float)ci[(size_t)row * NN + col] * INV_SCALE_F;
    out[NN * 40 + row] = expf(-cf);
  }
}

extern "C" void kernel_launch(void* const* d_in, const int* in_sizes, int n_in,
                              void* d_out, int out_size, void* d_ws,
                              size_t ws_size, hipStream_t stream) {
  const float* pred = (const float*)d_in[0];
  const float* gt = (const float*)d_in[1];
  float* out = (float*)d_out;
  int* ci = (int*)d_ws;  // 4 MB quantized cost (ws >= 4 MB proven in R1)

  // scratch in d_out's first 20 KB; every element overwritten by lap epilogue
  int* colv = (int*)out;
  int* colr = colv + NN;
  int* rm1 = colr + NN;
  int* rm2 = rm1 + NN;
  int* rj1 = rm2 + NN;

  cost_kernel<<<NN * NN / 256, 256, 0, stream>>>(pred, gt, ci);
  colmin_kernel<<<NN / 256, 256, 0, stream>>>(ci, colv, colr);
  rowmin_kernel<<<NN, 64, 0, stream>>>(ci, colv, rm1, rm2, rj1);
  lap_kernel<<<1, 64, 0, stream>>>(gt, ci, colv, colr, rm1, rm2, rj1, out);
}

// Round 6
// 14009.695 us; speedup vs baseline: 6.9006x; 1.6357x over previous
//
#include <hip/hip_runtime.h>
#include <math.h>

#define NN 1024
#define PP 20
#define LPC 16                 // columns per lane (64 x 16 = 1024)
#define SCALE_D 33554432.0     // 2^25
#define INV_SCALE_F (1.0f / 33554432.0f)
#define IMAX 0x7fffffff

// ---------- cost: replicate reference fp32 op order exactly ----------
__device__ __forceinline__ float cost_ij(const float* __restrict__ a,
                                         const float* __restrict__ b) {
#pragma clang fp contract(off)
  float s = 0.0f;
#pragma unroll
  for (int p = 0; p < PP; ++p) {
    float dx = a[2 * p]     - b[2 * p];
    float dy = a[2 * p + 1] - b[2 * p + 1];
    s += sqrtf(dx * dx + dy * dy);
  }
  return s / 20.0f;
}

// Quantized cost: c * 2^25 is an exact integer for all entries in [2^-2, 2^3]
// (fp32 ulp <= 2^-25 there). Computed in double => exact product + exact cast.
__global__ void cost_kernel(const float* __restrict__ pred,
                            const float* __restrict__ gt,
                            int* __restrict__ ci) {
  int id = blockIdx.x * blockDim.x + threadIdx.x;  // 0 .. NN*NN-1
  int i = id >> 10;
  int j = id & (NN - 1);
  float c = cost_ij(pred + i * 40, gt + j * 40);
  ci[id] = (int)((double)c * SCALE_D);
}

// ---------- column minima: colv[j] = min_i ci[i][j], first argmin ----------
__global__ void colmin_kernel(const int* __restrict__ ci,
                              int* __restrict__ colv,
                              int* __restrict__ colr) {
  int j = blockIdx.x * blockDim.x + threadIdx.x;  // 1024 threads total
  int mv = ci[j];
  int mi = 0;
#pragma unroll 8
  for (int i = 1; i < NN; ++i) {
    int c = ci[i * NN + j];
    if (c < mv) { mv = c; mi = i; }
  }
  colv[j] = mv;
  colr[j] = mi;
}

// ---------- per-row top-2 reduced costs vs v0 (for reduction transfer) ----
__global__ __launch_bounds__(64) void rowmin_kernel(
    const int* __restrict__ ci, const int* __restrict__ colv,
    int* __restrict__ rm1, int* __restrict__ rm2, int* __restrict__ rj1) {
  const int row = blockIdx.x;
  const int lane = threadIdx.x;
  const int* cr = ci + (size_t)row * NN + lane * LPC;
  const int* vr = colv + lane * LPC;
  int4 ca = ((const int4*)cr)[0], cb = ((const int4*)cr)[1],
       cc = ((const int4*)cr)[2], cd = ((const int4*)cr)[3];
  int4 va = ((const int4*)vr)[0], vb = ((const int4*)vr)[1],
       vc = ((const int4*)vr)[2], vd = ((const int4*)vr)[3];
  int c[LPC] = {ca.x, ca.y, ca.z, ca.w, cb.x, cb.y, cb.z, cb.w,
                cc.x, cc.y, cc.z, cc.w, cd.x, cd.y, cd.z, cd.w};
  int v[LPC] = {va.x, va.y, va.z, va.w, vb.x, vb.y, vb.z, vb.w,
                vc.x, vc.y, vc.z, vc.w, vd.x, vd.y, vd.z, vd.w};
  int m1 = IMAX, m2 = IMAX, c1 = IMAX;
#pragma unroll
  for (int q = 0; q < LPC; ++q) {
    const int d = c[q] - v[q];
    if (d < m1) { m2 = m1; m1 = d; c1 = lane * LPC + q; }
    else if (d < m2) m2 = d;
  }
#pragma unroll
  for (int m = 1; m < 64; m <<= 1) {
    const int pm1 = __shfl_xor(m1, m);
    const int pm2 = __shfl_xor(m2, m);
    const int pc1 = __shfl_xor(c1, m);
    const int hi = (m1 > pm1) ? m1 : pm1;
    const int lo2 = (m2 < pm2) ? m2 : pm2;
    if (pm1 < m1 || (pm1 == m1 && pc1 < c1)) { m1 = pm1; c1 = pc1; }
    m2 = (hi < lo2) ? hi : lo2;
  }
  if (lane == 0) { rm1[row] = m1; rm2[row] = m2; rj1[row] = c1; }
}

// ---------- wave64 min via DPP (LLVM AtomicOptimizer wave64 pattern) -------
// old=IMAX (min identity) for shifted-out lanes; after row_shr 1/2/4/8 +
// row_bcast 15/31 the scan leaves the full min in lane 63.
__device__ __forceinline__ int wave_min_bcast(int x) {
  int t;
  t = __builtin_amdgcn_update_dpp(IMAX, x, 0x111, 0xf, 0xf, false);  // row_shr:1
  x = (t < x) ? t : x;
  t = __builtin_amdgcn_update_dpp(IMAX, x, 0x112, 0xf, 0xf, false);  // row_shr:2
  x = (t < x) ? t : x;
  t = __builtin_amdgcn_update_dpp(IMAX, x, 0x114, 0xf, 0xf, false);  // row_shr:4
  x = (t < x) ? t : x;
  t = __builtin_amdgcn_update_dpp(IMAX, x, 0x118, 0xf, 0xf, false);  // row_shr:8
  x = (t < x) ? t : x;
  t = __builtin_amdgcn_update_dpp(IMAX, x, 0x142, 0xf, 0xf, false);  // row_bcast:15
  x = (t < x) ? t : x;
  t = __builtin_amdgcn_update_dpp(IMAX, x, 0x143, 0xf, 0xf, false);  // row_bcast:31
  x = (t < x) ? t : x;
  return __builtin_amdgcn_readlane(x, 63);
}

// ---------- integer JV: greedy + RT + adaptive ARR + Dijkstra ----------
// Single wave. Cross-lane LDS communication points carry __syncthreads()
// (compiler memory fences; ~free for one wave). The phase-3 pop loop has no
// LDS writes (registers only + uniform u_s reads) => barrier-free.
__global__ __launch_bounds__(64) void lap_kernel(
    const float* __restrict__ gt, const int* __restrict__ ci,
    const int* __restrict__ colv, const int* __restrict__ colr,
    const int* __restrict__ rm1, const int* __restrict__ rm2,
    const int* __restrict__ rj1, float* __restrict__ out) {
  const int lane = threadIdx.x;

  __shared__ int u_s[NN];
  __shared__ int row4col_s[NN];
  __shared__ int col4row_s[NN];
  __shared__ int path_s[NN];
  __shared__ int fla[NN];
  __shared__ int flb[NN];
  __shared__ int cnt_s;

  int v_r[LPC];   // v duals for owned cols [lane*16, lane*16+16)
  int sh_r[LPC];  // Dijkstra labels (keep settle value after settling)
  int kq_r[LPC];  // argmin key: == sh_r while active, IMAX when settled
  int pa_r[LPC];  // predecessor row per owned col
  int rc_r[LPC];  // register mirror of row4col for owned cols

  // ---- L2 priming: stream the 4 MB cost matrix into this CU's XCD L2 ----
  {
    const int4* p4 = (const int4*)ci;
    int ax = 0, ay = 0, az = 0, aw = 0;
    for (int it = 0; it < (NN * NN / 4) / 64; it += 8) {
#pragma unroll
      for (int uu = 0; uu < 8; ++uu) {
        const int4 tv = p4[(size_t)(it + uu) * 64 + lane];
        ax ^= tv.x; ay ^= tv.y; az ^= tv.z; aw ^= tv.w;
      }
    }
    asm volatile("" :: "v"(ax), "v"(ay), "v"(az), "v"(aw));  // keep loads live
  }

#pragma unroll
  for (int q = 0; q < LPC; ++q) {
    const int j = lane * LPC + q;
    u_s[j] = 0;
    row4col_s[j] = -1;
    col4row_s[j] = -1;
  }
  __syncthreads();

  // ---- phase 1: greedy claim via column argmins (serial, deterministic) ----
  if (lane == 0) {
    for (int j = 0; j < NN; ++j) {
      const int i = colr[j];
      if (col4row_s[i] < 0) { col4row_s[i] = j; row4col_s[j] = i; }
    }
  }
  __syncthreads();

  // ---- reduction transfer (Jacobi-parallel, integer-exact feasible) ----
#pragma unroll
  for (int q = 0; q < LPC; ++q) {
    const int j = lane * LPC + q;
    const int i = row4col_s[j];
    int vv = colv[j];
    if (i >= 0) {
      const int mu = (rj1[i] == j) ? rm2[i] : rm1[i];
      u_s[i] = mu;  // injective (row4col is injective)
      vv -= mu;
    }
    v_r[q] = vv;
  }
  if (lane == 0) {
    int n = 0;
    for (int i = 0; i < NN; ++i)
      if (col4row_s[i] < 0) fla[n++] = i;
    cnt_s = n;
  }
  __syncthreads();

  // ---- phase 2: augmenting row reduction, free-list driven, adaptive ----
  int use_a = 1;
  int prev = NN + 1;
  for (int pass = 0; pass < 16; ++pass) {
    const int cnt = cnt_s;
    if (cnt == 0 || cnt >= prev) break;  // done or no strict progress
    prev = cnt;
    int n2 = 0;  // lane 0's next-list count
    for (int idx = 0; idx < cnt; ++idx) {
      const int i = use_a ? fla[idx] : flb[idx];
      const int* cr = ci + (size_t)i * NN + lane * LPC;
      int4 ca = ((const int4*)cr)[0], cb = ((const int4*)cr)[1],
           cc = ((const int4*)cr)[2], cd = ((const int4*)cr)[3];
      int c[LPC] = {ca.x, ca.y, ca.z, ca.w, cb.x, cb.y, cb.z, cb.w,
                    cc.x, cc.y, cc.z, cc.w, cd.x, cd.y, cd.z, cd.w};
      int m1 = IMAX, m2 = IMAX, c1 = 0;
#pragma unroll
      for (int q = 0; q < LPC; ++q) {
        const int d = c[q] - v_r[q];
        if (d < m1) { m2 = m1; m1 = d; c1 = q; }
        else if (d < m2) m2 = d;
      }
      // cross-lane via DPP min + ballot (lowest lane = lowest col)
      const int m1g = wave_min_bcast(m1);
      const unsigned long long ball = __ballot(m1 == m1g);
      const int wl = __ffsll(ball) - 1;
      const int cand = (lane == wl) ? m2 : m1;  // drop one winning element
      const int m2g = wave_min_bcast(cand);
      const int j1 = (wl << 4) | __builtin_amdgcn_readlane(c1, wl);
      const int delta = m2g - m1g;  // >= 0
      if (lane == wl && delta > 0) {
#pragma unroll
        for (int q = 0; q < LPC; ++q)
          if (q == (j1 & 15)) v_r[q] -= delta;  // v[j1] = c[i][j1] - m2g
      }
      const int k = row4col_s[j1];  // pre-write value (fenced by barriers)
      __syncthreads();
      if (lane == 0) {
        u_s[i] = m2g;
        row4col_s[j1] = i;
        col4row_s[i] = j1;
        if (k >= 0) {
          col4row_s[k] = -1;
          if (use_a) flb[n2] = k; else fla[n2] = k;
          ++n2;
        }
      }
      __syncthreads();
    }
    if (lane == 0) cnt_s = n2;
    use_a ^= 1;
    __syncthreads();
  }

#pragma unroll
  for (int q = 0; q < LPC; ++q) rc_r[q] = row4col_s[lane * LPC + q];
  __syncthreads();

  // ---- phase 3: integer Dijkstra augmentation for remaining free rows ----
  const int nfree = cnt_s;
  for (int fi = 0; fi < nfree; ++fi) {
    const int r = use_a ? fla[fi] : flb[fi];
#pragma unroll
    for (int q = 0; q < LPC; ++q) { sh_r[q] = IMAX; kq_r[q] = IMAX; }
    int i = r;
    int mv = 0;
    int u_i = u_s[r];
    int sink;
    while (true) {
      const int* cr = ci + (size_t)i * NN + lane * LPC;
      int4 ca = ((const int4*)cr)[0], cb = ((const int4*)cr)[1],
           cc = ((const int4*)cr)[2], cd = ((const int4*)cr)[3];
      int c[LPC] = {ca.x, ca.y, ca.z, ca.w, cb.x, cb.y, cb.z, cb.w,
                    cc.x, cc.y, cc.z, cc.w, cd.x, cd.y, cd.z, cd.w};
      const int A = mv - u_i;
      // relax: settled cols can't improve (d >= mv >= settle value) => no mask
#pragma unroll
      for (int q = 0; q < LPC; ++q) {
        const int d = A + c[q] - v_r[q];
        const bool upd = d < sh_r[q];
        sh_r[q] = upd ? d : sh_r[q];
        kq_r[q] = upd ? d : kq_r[q];
        pa_r[q] = upd ? i : pa_r[q];
      }
      // in-lane argmin tree on kq (strict < keeps lowest q), carrying (q, rc)
      int t1k[8], t1e[8], t1r[8];
#pragma unroll
      for (int q = 0; q < 8; ++q) {
        const bool b = kq_r[2 * q + 1] < kq_r[2 * q];
        t1k[q] = b ? kq_r[2 * q + 1] : kq_r[2 * q];
        t1e[q] = b ? 2 * q + 1 : 2 * q;
        t1r[q] = b ? rc_r[2 * q + 1] : rc_r[2 * q];
      }
      int t2k[4], t2e[4], t2r[4];
#pragma unroll
      for (int q = 0; q < 4; ++q) {
        const bool b = t1k[2 * q + 1] < t1k[2 * q];
        t2k[q] = b ? t1k[2 * q + 1] : t1k[2 * q];
        t2e[q] = b ? t1e[2 * q + 1] : t1e[2 * q];
        t2r[q] = b ? t1r[2 * q + 1] : t1r[2 * q];
      }
      int t3k[2], t3e[2], t3r[2];
#pragma unroll
      for (int q = 0; q < 2; ++q) {
        const bool b = t2k[2 * q + 1] < t2k[2 * q];
        t3k[q] = b ? t2k[2 * q + 1] : t2k[2 * q];
        t3e[q] = b ? t2e[2 * q + 1] : t2e[2 * q];
        t3r[q] = b ? t2r[2 * q + 1] : t2r[2 * q];
      }
      const bool b0 = t3k[1] < t3k[0];
      const int bs = b0 ? t3k[1] : t3k[0];
      const int bq = b0 ? t3e[1] : t3e[0];
      const int brc = b0 ? t3r[1] : t3r[0];
      // cross-lane: DPP min + ballot winner (lowest lane = lowest col)
      const int minkey = wave_min_bcast(bs);
      const unsigned long long ball = __ballot(bs == minkey);
      const int wl = __ffsll(ball) - 1;
      const int kcol = (wl << 4) | __builtin_amdgcn_readlane(bq, wl);
      const int krc = __builtin_amdgcn_readlane(brc, wl);
      mv = minkey;
      if (krc < 0) { sink = kcol; break; }
      if (lane == (kcol >> 4)) {  // settle kcol: remove from argmin domain
#pragma unroll
        for (int q = 0; q < LPC; ++q)
          if (q == (kcol & 15)) kq_r[q] = IMAX;
      }
      i = krc;
      u_i = u_s[i];  // uniform LDS read, hidden under next row load
    }
    // dual updates: settled <=> kq==IMAX && sh<IMAX (sink excluded: delta 0)
#pragma unroll
    for (int q = 0; q < LPC; ++q) {
      if (kq_r[q] == IMAX && sh_r[q] != IMAX) {
        const int delta = mv - sh_r[q];
        const int i2 = rc_r[q];
        if (i2 >= 0) u_s[i2] += delta;  // injective addresses
        v_r[q] -= delta;
      }
      path_s[lane * LPC + q] = pa_r[q];
    }
    if (lane == 0) u_s[r] += mv;
    __syncthreads();
    if (lane == 0) {
      int j = sink;
      while (true) {
        const int i2 = path_s[j];
        row4col_s[j] = i2;
        const int jn = col4row_s[i2];
        col4row_s[i2] = j;
        j = jn;
        if (i2 == r) break;
      }
    }
    __syncthreads();
#pragma unroll
    for (int q = 0; q < LPC; ++q) rc_r[q] = row4col_s[lane * LPC + q];
  }
  __syncthreads();

  // ---------- outputs: 16 rows per lane ----------
#pragma unroll
  for (int q = 0; q < LPC; ++q) {
    const int row = lane * LPC + q;
    const int col = col4row_s[row];
    const float4* g4 = (const float4*)(gt + (size_t)col * 40);
    float4* o4 = (float4*)(out + (size_t)row * 40);
#pragma unroll
    for (int w = 0; w < 10; ++w) o4[w] = g4[w];
    // exact fp32 recovery: ci has <=24 significant bits, scale is pow2
    const float cf = (float)ci[(size_t)row * NN + col] * INV_SCALE_F;
    out[NN * 40 + row] = expf(-cf);
  }
}

extern "C" void kernel_launch(void* const* d_in, const int* in_sizes, int n_in,
                              void* d_out, int out_size, void* d_ws,
                              size_t ws_size, hipStream_t stream) {
  const float* pred = (const float*)d_in[0];
  const float* gt = (const float*)d_in[1];
  float* out = (float*)d_out;
  int* ci = (int*)d_ws;  // 4 MB quantized cost

  // scratch in d_out's first 20 KB; every element overwritten by lap epilogue
  int* colv = (int*)out;
  int* colr = colv + NN;
  int* rm1 = colr + NN;
  int* rm2 = rm1 + NN;
  int* rj1 = rm2 + NN;

  cost_kernel<<<NN * NN / 256, 256, 0, stream>>>(pred, gt, ci);
  colmin_kernel<<<NN / 256, 256, 0, stream>>>(ci, colv, colr);
  rowmin_kernel<<<NN, 64, 0, stream>>>(ci, colv, rm1, rm2, rj1);
  lap_kernel<<<1, 64, 0, stream>>>(gt, ci, colv, colr, rm1, rm2, rj1, out);
}

// Round 7
// 9873.507 us; speedup vs baseline: 9.7913x; 1.4189x over previous
//
#include <hip/hip_runtime.h>
#include <math.h>

#define NN 1024
#define PP 20
#define LPC 16                 // columns per lane (64 x 16 = 1024)
#define SCALE_D 33554432.0     // 2^25
#define INV_SCALE_F (1.0f / 33554432.0f)
#define IMAX 0x7fffffff
#define ARR_CAP 4096           // continuous-ARR step cap (termination guard)

// ---------- cost: replicate reference fp32 op order exactly ----------
__device__ __forceinline__ float cost_ij(const float* __restrict__ a,
                                         const float* __restrict__ b) {
#pragma clang fp contract(off)
  float s = 0.0f;
#pragma unroll
  for (int p = 0; p < PP; ++p) {
    float dx = a[2 * p]     - b[2 * p];
    float dy = a[2 * p + 1] - b[2 * p + 1];
    s += sqrtf(dx * dx + dy * dy);
  }
  return s / 20.0f;
}

// Quantized cost: c * 2^25 is an exact integer for all entries in [2^-2, 2^3]
// (fp32 ulp <= 2^-25 there). Computed in double => exact product + exact cast.
__global__ void cost_kernel(const float* __restrict__ pred,
                            const float* __restrict__ gt,
                            int* __restrict__ ci) {
  int id = blockIdx.x * blockDim.x + threadIdx.x;  // 0 .. NN*NN-1
  int i = id >> 10;
  int j = id & (NN - 1);
  float c = cost_ij(pred + i * 40, gt + j * 40);
  ci[id] = (int)((double)c * SCALE_D);
}

// ---------- column minima: colv[j] = min_i ci[i][j], first argmin ----------
__global__ void colmin_kernel(const int* __restrict__ ci,
                              int* __restrict__ colv,
                              int* __restrict__ colr) {
  int j = blockIdx.x * blockDim.x + threadIdx.x;  // 1024 threads total
  int mv = ci[j];
  int mi = 0;
#pragma unroll 8
  for (int i = 1; i < NN; ++i) {
    int c = ci[i * NN + j];
    if (c < mv) { mv = c; mi = i; }
  }
  colv[j] = mv;
  colr[j] = mi;
}

// ---------- per-row top-2 reduced costs vs v0 (for reduction transfer) ----
__global__ __launch_bounds__(64) void rowmin_kernel(
    const int* __restrict__ ci, const int* __restrict__ colv,
    int* __restrict__ rm1, int* __restrict__ rm2, int* __restrict__ rj1) {
  const int row = blockIdx.x;
  const int lane = threadIdx.x;
  const int* cr = ci + (size_t)row * NN + lane * LPC;
  const int* vr = colv + lane * LPC;
  int4 ca = ((const int4*)cr)[0], cb = ((const int4*)cr)[1],
       cc = ((const int4*)cr)[2], cd = ((const int4*)cr)[3];
  int4 va = ((const int4*)vr)[0], vb = ((const int4*)vr)[1],
       vc = ((const int4*)vr)[2], vd = ((const int4*)vr)[3];
  int c[LPC] = {ca.x, ca.y, ca.z, ca.w, cb.x, cb.y, cb.z, cb.w,
                cc.x, cc.y, cc.z, cc.w, cd.x, cd.y, cd.z, cd.w};
  int v[LPC] = {va.x, va.y, va.z, va.w, vb.x, vb.y, vb.z, vb.w,
                vc.x, vc.y, vc.z, vc.w, vd.x, vd.y, vd.z, vd.w};
  int m1 = IMAX, m2 = IMAX, c1 = IMAX;
#pragma unroll
  for (int q = 0; q < LPC; ++q) {
    const int d = c[q] - v[q];
    if (d < m1) { m2 = m1; m1 = d; c1 = lane * LPC + q; }
    else if (d < m2) m2 = d;
  }
#pragma unroll
  for (int m = 1; m < 64; m <<= 1) {
    const int pm1 = __shfl_xor(m1, m);
    const int pm2 = __shfl_xor(m2, m);
    const int pc1 = __shfl_xor(c1, m);
    const int hi = (m1 > pm1) ? m1 : pm1;
    const int lo2 = (m2 < pm2) ? m2 : pm2;
    if (pm1 < m1 || (pm1 == m1 && pc1 < c1)) { m1 = pm1; c1 = pc1; }
    m2 = (hi < lo2) ? hi : lo2;
  }
  if (lane == 0) { rm1[row] = m1; rm2[row] = m2; rj1[row] = c1; }
}

// ---------- wave64 min via DPP (LLVM AtomicOptimizer wave64 pattern) -------
__device__ __forceinline__ int wave_min_bcast(int x) {
  int t;
  t = __builtin_amdgcn_update_dpp(IMAX, x, 0x111, 0xf, 0xf, false);  // row_shr:1
  x = (t < x) ? t : x;
  t = __builtin_amdgcn_update_dpp(IMAX, x, 0x112, 0xf, 0xf, false);  // row_shr:2
  x = (t < x) ? t : x;
  t = __builtin_amdgcn_update_dpp(IMAX, x, 0x114, 0xf, 0xf, false);  // row_shr:4
  x = (t < x) ? t : x;
  t = __builtin_amdgcn_update_dpp(IMAX, x, 0x118, 0xf, 0xf, false);  // row_shr:8
  x = (t < x) ? t : x;
  t = __builtin_amdgcn_update_dpp(IMAX, x, 0x142, 0xf, 0xf, false);  // row_bcast:15
  x = (t < x) ? t : x;
  t = __builtin_amdgcn_update_dpp(IMAX, x, 0x143, 0xf, 0xf, false);  // row_bcast:31
  x = (t < x) ? t : x;
  return __builtin_amdgcn_readlane(x, 63);
}

// ---------- integer JV: greedy + RT + continuous ARR + Dijkstra ----------
__global__ __launch_bounds__(64) void lap_kernel(
    const float* __restrict__ gt, const int* __restrict__ ci,
    const int* __restrict__ colv, const int* __restrict__ colr,
    const int* __restrict__ rm1, const int* __restrict__ rm2,
    const int* __restrict__ rj1, float* __restrict__ out) {
  const int lane = threadIdx.x;

  __shared__ int u_s[NN];
  __shared__ int row4col_s[NN];
  __shared__ int col4row_s[NN];
  __shared__ int path_s[NN];
  __shared__ int queue_s[NN + ARR_CAP];  // displacement ring (head..tail)

  int nv_r[LPC];  // NEGATED v duals for owned cols (enables v_add3 relax)
  int sh_r[LPC];  // Dijkstra labels (keep settle value after settling)
  int kq_r[LPC];  // argmin key: == sh_r while active, IMAX when settled
  int pa_r[LPC];  // predecessor row per owned col
  int rc_r[LPC];  // register mirror of row4col for owned cols

  // ---- L2 priming: stream the 4 MB cost matrix into this CU's XCD L2 ----
  {
    const int4* p4 = (const int4*)ci;
    int ax = 0, ay = 0, az = 0, aw = 0;
    for (int it = 0; it < (NN * NN / 4) / 64; it += 8) {
#pragma unroll
      for (int uu = 0; uu < 8; ++uu) {
        const int4 tv = p4[(size_t)(it + uu) * 64 + lane];
        ax ^= tv.x; ay ^= tv.y; az ^= tv.z; aw ^= tv.w;
      }
    }
    asm volatile("" :: "v"(ax), "v"(ay), "v"(az), "v"(aw));  // keep loads live
  }

#pragma unroll
  for (int q = 0; q < LPC; ++q) {
    const int j = lane * LPC + q;
    u_s[j] = 0;
    row4col_s[j] = -1;
    col4row_s[j] = -1;
  }
  __syncthreads();

  // ---- phase 1: greedy claim via column argmins (serial, deterministic) ----
  if (lane == 0) {
    for (int j = 0; j < NN; ++j) {
      const int i = colr[j];
      if (col4row_s[i] < 0) { col4row_s[i] = j; row4col_s[j] = i; }
    }
  }
  __syncthreads();

  // ---- reduction transfer (Jacobi-parallel, integer-exact feasible) ----
#pragma unroll
  for (int q = 0; q < LPC; ++q) {
    const int j = lane * LPC + q;
    const int i = row4col_s[j];
    int nvv = -colv[j];
    if (i >= 0) {
      const int mu = (rj1[i] == j) ? rm2[i] : rm1[i];
      u_s[i] = mu;  // injective (row4col is injective)
      nvv += mu;
    }
    nv_r[q] = nvv;
  }
  if (lane == 0) {
    int n = 0;
    for (int i = 0; i < NN; ++i)
      if (col4row_s[i] < 0) queue_s[n++] = i;
    path_s[0] = n;  // temp: initial free count
  }
  __syncthreads();
  int head = 0;
  int tail = path_s[0];  // uniform
  __syncthreads();

  // ---- phase 2: continuous augmenting row reduction (JV87 queue) ----
  for (int step = 0; step < ARR_CAP && head < tail; ++step) {
    const int i = queue_s[head];  // uniform read
    ++head;
    const int* cr = ci + (size_t)i * NN + lane * LPC;
    int4 ca = ((const int4*)cr)[0], cb = ((const int4*)cr)[1],
         cc = ((const int4*)cr)[2], cd = ((const int4*)cr)[3];
    int c[LPC] = {ca.x, ca.y, ca.z, ca.w, cb.x, cb.y, cb.z, cb.w,
                  cc.x, cc.y, cc.z, cc.w, cd.x, cd.y, cd.z, cd.w};
    int m1 = IMAX, m2 = IMAX, c1 = 0;
#pragma unroll
    for (int q = 0; q < LPC; ++q) {
      const int d = c[q] + nv_r[q];
      if (d < m1) { m2 = m1; m1 = d; c1 = q; }
      else if (d < m2) m2 = d;
    }
    // cross-lane via DPP min + ballot (lowest lane = lowest col)
    const int m1g = wave_min_bcast(m1);
    const unsigned long long ball = __ballot(m1 == m1g);
    const int wl = __ffsll(ball) - 1;
    const int cand = (lane == wl) ? m2 : m1;  // drop one winning element
    const int m2g = wave_min_bcast(cand);
    const int j1 = (wl << 4) | __builtin_amdgcn_readlane(c1, wl);
    const int delta = m2g - m1g;  // >= 0
    if (lane == wl && delta > 0) {
#pragma unroll
      for (int q = 0; q < LPC; ++q)
        if (q == (j1 & 15)) nv_r[q] += delta;  // v[j1] = c[i][j1] - m2g
    }
    const int k = row4col_s[j1];  // pre-write value (fenced by barriers)
    __syncthreads();
    if (lane == 0) {
      u_s[i] = m2g;
      row4col_s[j1] = i;
      col4row_s[i] = j1;
      if (k >= 0) {
        col4row_s[k] = -1;
        queue_s[tail] = k;
      }
    }
    if (k >= 0) ++tail;  // uniform (k from uniform LDS read)
    __syncthreads();
  }

#pragma unroll
  for (int q = 0; q < LPC; ++q) rc_r[q] = row4col_s[lane * LPC + q];
  __syncthreads();

  // ---- phase 3: integer Dijkstra augmentation for queue残 rows ----
  const int nfree = tail - head;
  for (int fi = 0; fi < nfree; ++fi) {
    const int r = queue_s[head + fi];  // uniform
#pragma unroll
    for (int q = 0; q < LPC; ++q) { sh_r[q] = IMAX; kq_r[q] = IMAX; }
    int i = r;
    int mv = 0;
    int A = __builtin_amdgcn_readfirstlane(-u_s[r]);  // A = mv - u_i (SGPR)
    int sink;
    while (true) {
      const int* cr = ci + (size_t)i * NN + lane * LPC;
      int4 ca = ((const int4*)cr)[0], cb = ((const int4*)cr)[1],
           cc = ((const int4*)cr)[2], cd = ((const int4*)cr)[3];
      int c[LPC] = {ca.x, ca.y, ca.z, ca.w, cb.x, cb.y, cb.z, cb.w,
                    cc.x, cc.y, cc.z, cc.w, cd.x, cd.y, cd.z, cd.w};
      // relax: d = A + c + nv  (v_add3, one SGPR operand)
#pragma unroll
      for (int q = 0; q < LPC; ++q) {
        const int d = A + c[q] + nv_r[q];
        const bool upd = d < sh_r[q];
        sh_r[q] = upd ? d : sh_r[q];
        kq_r[q] = upd ? d : kq_r[q];
        pa_r[q] = upd ? i : pa_r[q];
      }
      // in-lane argmin tree on kq (strict < keeps lowest q), carrying (q, rc)
      int t1k[8], t1e[8], t1r[8];
#pragma unroll
      for (int q = 0; q < 8; ++q) {
        const bool b = kq_r[2 * q + 1] < kq_r[2 * q];
        t1k[q] = b ? kq_r[2 * q + 1] : kq_r[2 * q];
        t1e[q] = b ? 2 * q + 1 : 2 * q;
        t1r[q] = b ? rc_r[2 * q + 1] : rc_r[2 * q];
      }
      int t2k[4], t2e[4], t2r[4];
#pragma unroll
      for (int q = 0; q < 4; ++q) {
        const bool b = t1k[2 * q + 1] < t1k[2 * q];
        t2k[q] = b ? t1k[2 * q + 1] : t1k[2 * q];
        t2e[q] = b ? t1e[2 * q + 1] : t1e[2 * q];
        t2r[q] = b ? t1r[2 * q + 1] : t1r[2 * q];
      }
      int t3k[2], t3e[2], t3r[2];
#pragma unroll
      for (int q = 0; q < 2; ++q) {
        const bool b = t2k[2 * q + 1] < t2k[2 * q];
        t3k[q] = b ? t2k[2 * q + 1] : t2k[2 * q];
        t3e[q] = b ? t2e[2 * q + 1] : t2e[2 * q];
        t3r[q] = b ? t2r[2 * q + 1] : t2r[2 * q];
      }
      const bool b0 = t3k[1] < t3k[0];
      const int bs = b0 ? t3k[1] : t3k[0];
      const int bq = b0 ? t3e[1] : t3e[0];
      const int brc = b0 ? t3r[1] : t3r[0];
      // cross-lane: DPP min + ballot winner (lowest lane = lowest col)
      const int minkey = wave_min_bcast(bs);
      const unsigned long long ball = __ballot(bs == minkey);
      const int wl = __ffsll(ball) - 1;
      const int kcol = (wl << 4) | __builtin_amdgcn_readlane(bq, wl);
      const int krc = __builtin_amdgcn_readlane(brc, wl);
      mv = minkey;
      if (krc < 0) { sink = kcol; break; }
      if (lane == (kcol >> 4)) {  // settle kcol: remove from argmin domain
#pragma unroll
        for (int q = 0; q < LPC; ++q)
          if (q == (kcol & 15)) kq_r[q] = IMAX;
      }
      i = krc;
      A = __builtin_amdgcn_readfirstlane(mv - u_s[i]);  // hidden under row load
    }
    // dual updates: settled <=> kq==IMAX && sh<IMAX (sink excluded: delta 0)
#pragma unroll
    for (int q = 0; q < LPC; ++q) {
      if (kq_r[q] == IMAX && sh_r[q] != IMAX) {
        const int delta = mv - sh_r[q];
        const int i2 = rc_r[q];
        if (i2 >= 0) u_s[i2] += delta;  // injective addresses
        nv_r[q] += delta;               // v -= delta
      }
      path_s[lane * LPC + q] = pa_r[q];
    }
    if (lane == 0) u_s[r] += mv;
    __syncthreads();
    if (lane == 0) {
      int j = sink;
      while (true) {
        const int i2 = path_s[j];
        row4col_s[j] = i2;
        const int jn = col4row_s[i2];
        col4row_s[i2] = j;
        j = jn;
        if (i2 == r) break;
      }
    }
    __syncthreads();
#pragma unroll
    for (int q = 0; q < LPC; ++q) rc_r[q] = row4col_s[lane * LPC + q];
  }
  __syncthreads();

  // ---------- outputs: 16 rows per lane ----------
#pragma unroll
  for (int q = 0; q < LPC; ++q) {
    const int row = lane * LPC + q;
    const int col = col4row_s[row];
    const float4* g4 = (const float4*)(gt + (size_t)col * 40);
    float4* o4 = (float4*)(out + (size_t)row * 40);
#pragma unroll
    for (int w = 0; w < 10; ++w) o4[w] = g4[w];
    // exact fp32 recovery: ci has <=24 significant bits, scale is pow2
    const float cf = (float)ci[(size_t)row * NN + col] * INV_SCALE_F;
    out[NN * 40 + row] = expf(-cf);
  }
}

extern "C" void kernel_launch(void* const* d_in, const int* in_sizes, int n_in,
                              void* d_out, int out_size, void* d_ws,
                              size_t ws_size, hipStream_t stream) {
  const float* pred = (const float*)d_in[0];
  const float* gt = (const float*)d_in[1];
  float* out = (float*)d_out;
  int* ci = (int*)d_ws;  // 4 MB quantized cost

  // scratch in d_out's first 20 KB; every element overwritten by lap epilogue
  int* colv = (int*)out;
  int* colr = colv + NN;
  int* rm1 = colr + NN;
  int* rm2 = rm1 + NN;
  int* rj1 = rm2 + NN;

  cost_kernel<<<NN * NN / 256, 256, 0, stream>>>(pred, gt, ci);
  colmin_kernel<<<NN / 256, 256, 0, stream>>>(ci, colv, colr);
  rowmin_kernel<<<NN, 64, 0, stream>>>(ci, colv, rm1, rm2, rj1);
  lap_kernel<<<1, 64, 0, stream>>>(gt, ci, colv, colr, rm1, rm2, rj1, out);
}